// Round 7
// baseline (112.411 us; speedup 1.0000x reference)
//
#include <hip/hip_runtime.h>
#include <hip/hip_bf16.h>

// out[b,c,y,x] = sum_{dy,dx} f[b,c,y+dy-3,x+dx-3] * ker[b,dy,dx,y,x]
// MFMA per 16-px strip: D[m=c][n=px] += A[m][k] * B[k][n];
//   A[m][k] = bf16(feat[c0+m, y+dy-3, gx0-4+k])   (VGPR ring, 7 named slots)
//   B[k][n] = bf16(ker[dy, k-n-1, y, gx0+n]) for k-n-1 in [0,6], else 0
// Block = 384 thr = 6 waves, each wave owns one 16-channel tile of the same
// 16-px strip. BT (band-layout K taps) shared in LDS, double-buffered.
// Grid 1024 -> 2 resident blocks/CU for cross-block latency hiding.

#define BATCH 4
#define CHAN 96
#define HW_ 256
#define HWPIX 65536
#define KS 7
#define XT 16
#define YT 16
#define NTHR 384
#define BT_K 24                    // stored k-dim (band max 22, pad to 24)
#define BT_NROW (KS * BT_K)        // 168 shorts per n
#define BT_BUF (16 * BT_NROW)      // 2688 shorts per buffer
#define KVALS (KS * KS * XT)       // 784
#define FTOT ((size_t)BATCH * CHAN * HWPIX)

typedef __attribute__((ext_vector_type(8))) short short8v;
typedef __attribute__((ext_vector_type(4))) float f32x4;

union S8 { short8v s; unsigned u[4]; };

static __device__ __forceinline__ unsigned pkbf(float a, float b) {
    union { __hip_bfloat162 h; unsigned u; } c;
    c.h = __float22bfloat162_rn(make_float2(a, b));
    return c.u;
}
static __device__ __forceinline__ short bfbits(float x) {
    union { __hip_bfloat16 h; short s; } c;
    c.h = __float2bfloat16(x);
    return c.s;
}

__global__ __launch_bounds__(NTHR, 3)
void svconv_mfma5(const float* __restrict__ K_, const float* __restrict__ F_,
                  float* __restrict__ O_) {
    __shared__ short BT[2 * BT_BUF];   // 10752 B

    const int tid = threadIdx.x;
    const int xt = blockIdx.x, yt = blockIdx.y, b = blockIdx.z;
    const int gx0 = xt * XT, gy0 = yt * YT;
    const int wave = tid >> 6, lane = tid & 63;   // wave = c-tile 0..5
    const int n = lane & 15, kb = lane >> 4;      // frag col / k-group
    const int c0 = wave * 16;

    // ---- A addressing (y-invariant). kb=3 lanes alias kb=0 (their B is 0).
    const int kcl = (kb == 3) ? 0 : kb;
    const int xs = gx0 - 4 + kcl * 8;             // xs % 4 == 0
    const float* abase = F_ + ((size_t)(b * CHAN + c0 + n)) * HWPIX + xs;
    const float* lo = F_;
    const float* hiq = F_ + FTOT - 4;

    // x-validity masks (each float4 element-pair homogeneous in validity)
    unsigned xm0, xm1, xm2, xm3;
    {
        unsigned m[4];
#pragma unroll
        for (int i = 0; i < 4; ++i) {
            unsigned a0 = ((unsigned)(xs + 2 * i) < (unsigned)HW_) ? 0xFFFFu : 0u;
            unsigned a1 = ((unsigned)(xs + 2 * i + 1) < (unsigned)HW_) ? 0xFFFFu : 0u;
            m[i] = a0 | (a1 << 16);
        }
        xm0 = m[0]; xm1 = m[1]; xm2 = m[2]; xm3 = m[3];
    }

#define AISSUE(F0, F1, yr) do {                                           \
        const float* p = abase + (size_t)(yr) * HW_;                      \
        const float* q0 = p;     q0 = q0 < lo ? lo : (q0 > hiq ? hiq : q0); \
        const float* q1 = p + 4; q1 = q1 < lo ? lo : (q1 > hiq ? hiq : q1); \
        F0 = *(const float4*)q0; F1 = *(const float4*)q1;                 \
    } while (0)

#define ACOMMIT(DST, F0, F1, YOK) do {                                    \
        S8 v_;                                                            \
        if (YOK) {                                                        \
            v_.u[0] = pkbf(F0.x, F0.y) & xm0;                             \
            v_.u[1] = pkbf(F0.z, F0.w) & xm1;                             \
            v_.u[2] = pkbf(F1.x, F1.y) & xm2;                             \
            v_.u[3] = pkbf(F1.z, F1.w) & xm3;                             \
        } else { v_.u[0] = 0; v_.u[1] = 0; v_.u[2] = 0; v_.u[3] = 0; }    \
        DST = v_.s;                                                       \
    } while (0)

    // ---- K band staging slots (3 per thread, named)
    int kg0, kg1, kg2, kld0, kld1, kld2;
    {
        int kg[3], kld[3];
#pragma unroll
        for (int i = 0; i < 3; ++i) {
            int idx = tid + NTHR * i;
            if (idx < KVALS) {
                int dydx = idx >> 4, xl = idx & 15;
                int dy = dydx / KS, dx = dydx - KS * dy;
                kg[i] = dydx * HWPIX + gx0 + xl;
                kld[i] = xl * BT_NROW + dy * BT_K + (xl + dx + 1);
            } else { kg[i] = 0; kld[i] = -1; }
        }
        kg0 = kg[0]; kg1 = kg[1]; kg2 = kg[2];
        kld0 = kld[0]; kld1 = kld[1]; kld2 = kld[2];
    }
    const float* Kb = K_ + (size_t)b * KS * KS * HWPIX;

    // ---- zero both BT buffers (non-band slots stay 0 forever)
    {
        unsigned* bt32 = (unsigned*)BT;   // 2688 dwords
#pragma unroll
        for (int i = 0; i < 7; ++i) bt32[tid + NTHR * i] = 0u;
    }

    // ---- prologue loads: K row gy0; A rows gy0-3..gy0+3 (all issued, then committed)
    float krA = (kld0 >= 0) ? Kb[kg0 + (size_t)gy0 * HW_] : 0.f;
    float krB = (kld1 >= 0) ? Kb[kg1 + (size_t)gy0 * HW_] : 0.f;
    float krC = (kld2 >= 0) ? Kb[kg2 + (size_t)gy0 * HW_] : 0.f;

    float4 fa0, fa1, fb0, fb1, fc0, fc1, fd0, fd1, fe0, fe1, ff0, ff1, fg0, fg1;
    AISSUE(fa0, fa1, gy0 - 3); AISSUE(fb0, fb1, gy0 - 2);
    AISSUE(fc0, fc1, gy0 - 1); AISSUE(fd0, fd1, gy0);
    AISSUE(fe0, fe1, gy0 + 1); AISSUE(ff0, ff1, gy0 + 2);
    AISSUE(fg0, fg1, gy0 + 3);

    __syncthreads();   // BT zeros visible before band writes

    short8v s0, s1, s2, s3, s4, s5, s6;   // A ring (row y-3 .. y+3)
    ACOMMIT(s0, fa0, fa1, gy0 - 3 >= 0);
    ACOMMIT(s1, fb0, fb1, gy0 - 2 >= 0);
    ACOMMIT(s2, fc0, fc1, gy0 - 1 >= 0);
    ACOMMIT(s3, fd0, fd1, true);
    ACOMMIT(s4, fe0, fe1, true);
    ACOMMIT(s5, ff0, ff1, true);
    ACOMMIT(s6, fg0, fg1, true);

    // band-write K row gy0 -> buf0 (visible after first loop-top barrier)
    if (kld0 >= 0) BT[kld0] = bfbits(krA);
    if (kld1 >= 0) BT[kld1] = bfbits(krB);
    if (kld2 >= 0) BT[kld2] = bfbits(krC);

    const short8v bzero = {0, 0, 0, 0, 0, 0, 0, 0};
    float* ob = O_ + ((size_t)(b * CHAN + c0 + kb * 4)) * HWPIX + gx0 + n;
    const int kb8 = kb * 8;

    for (int t = 0; t < YT; ++t) {
        const int y = gy0 + t;
        __syncthreads();   // BT[t&1] band writes visible; other buffer free

        // early: issue next K row + next A row loads (consumed at loop bottom)
        float kA = 0.f, kB = 0.f, kC = 0.f;
        if (t < YT - 1) {
            const size_t yo = (size_t)(y + 1) * HW_;
            if (kld0 >= 0) kA = Kb[kg0 + yo];
            if (kld1 >= 0) kB = Kb[kg1 + yo];
            if (kld2 >= 0) kC = Kb[kg2 + yo];
        }
        const bool pyok = (y + 4 < HW_);
        float4 g0, g1;
        AISSUE(g0, g1, y + 4);

        // B fragments from BT[t&1] (named, 7x ds_read_b128)
        const short* btp = BT + (t & 1) * BT_BUF + n * BT_NROW + kb8;
        short8v b0, b1, b2, b3, b4, b5, b6;
        if (kb < 3) {
            b0 = *(const short8v*)(btp);
            b1 = *(const short8v*)(btp + 1 * BT_K);
            b2 = *(const short8v*)(btp + 2 * BT_K);
            b3 = *(const short8v*)(btp + 3 * BT_K);
            b4 = *(const short8v*)(btp + 4 * BT_K);
            b5 = *(const short8v*)(btp + 5 * BT_K);
            b6 = *(const short8v*)(btp + 6 * BT_K);
        } else {
            b0 = bzero; b1 = bzero; b2 = bzero; b3 = bzero;
            b4 = bzero; b5 = bzero; b6 = bzero;
        }

        // MFMA chain over dy (ring slots are named registers)
        f32x4 acc = {0.f, 0.f, 0.f, 0.f};
        acc = __builtin_amdgcn_mfma_f32_16x16x32_bf16(s0, b0, acc, 0, 0, 0);
        acc = __builtin_amdgcn_mfma_f32_16x16x32_bf16(s1, b1, acc, 0, 0, 0);
        acc = __builtin_amdgcn_mfma_f32_16x16x32_bf16(s2, b2, acc, 0, 0, 0);
        acc = __builtin_amdgcn_mfma_f32_16x16x32_bf16(s3, b3, acc, 0, 0, 0);
        acc = __builtin_amdgcn_mfma_f32_16x16x32_bf16(s4, b4, acc, 0, 0, 0);
        acc = __builtin_amdgcn_mfma_f32_16x16x32_bf16(s5, b5, acc, 0, 0, 0);
        acc = __builtin_amdgcn_mfma_f32_16x16x32_bf16(s6, b6, acc, 0, 0, 0);

        // stores: D col = n (px), row = kb*4+r (channel)
        {
            float* op = ob + (size_t)y * HW_;
            op[0]                    = acc[0];
            op[(size_t)1 * HWPIX]    = acc[1];
            op[(size_t)2 * HWPIX]    = acc[2];
            op[(size_t)3 * HWPIX]    = acc[3];
        }

        // shift ring, commit row y+4
        s0 = s1; s1 = s2; s2 = s3; s3 = s4; s4 = s5; s5 = s6;
        ACOMMIT(s6, g0, g1, pyok);

        // band-write K row y+1 into the opposite buffer
        if (t < YT - 1) {
            short* btw = BT + ((t + 1) & 1) * BT_BUF;
            if (kld0 >= 0) btw[kld0] = bfbits(kA);
            if (kld1 >= 0) btw[kld1] = bfbits(kB);
            if (kld2 >= 0) btw[kld2] = bfbits(kC);
        }
    }
}

extern "C" void kernel_launch(void* const* d_in, const int* in_sizes, int n_in,
                              void* d_out, int out_size, void* d_ws, size_t ws_size,
                              hipStream_t stream) {
    const float* kernels  = (const float*)d_in[0];  // [4,7,7,256,256]
    const float* features = (const float*)d_in[1];  // [4,96,256,256]
    float* out = (float*)d_out;                     // [4,96,256,256]

    dim3 grid(HW_ / XT, HW_ / YT, BATCH);  // (16, 16, 4) = 1024 blocks
    dim3 block(NTHR);
    svconv_mfma5<<<grid, block, 0, stream>>>(kernels, features, out);
}